// Round 2
// baseline (1245.555 us; speedup 1.0000x reference)
//
#include <hip/hip_runtime.h>

// RoutedSelfAttention on MI355X.
// Pipeline: meanpool -> router -> cast x (bf16) -> transpose-cast W (bf16, W^T)
//           -> MFMA GEMM qkv (+fused RoPE) -> fp32 flash attention -> MFMA GEMM out proj.
// Internal bf16 stored as raw unsigned short (RNE rounding) to avoid hip_bf16 API drift.

typedef __attribute__((ext_vector_type(8))) short bf16x8;   // 8 bf16 = 4 VGPR (A/B frag)
typedef __attribute__((ext_vector_type(4))) float f32x4;    // C/D frag

typedef const __attribute__((address_space(1))) unsigned short* gas_t;
typedef __attribute__((address_space(3))) unsigned short* las_t;

#define OFF_PART   (0ull)            // [32][16][1024] f32 partial mean sums (2 MB)
#define OFF_ROUTES (2ull << 20)      // [32] int
#define OFF_XB     (3ull << 20)      // x bf16 [32][512][1024] (32 MB); reused as ctx after gemm<0>
#define OFF_WT     (40ull << 20)     // W^T bf16 [4][8][1024][1024] (64 MB)
#define OFF_QKV    (112ull << 20)    // q,k,v bf16 [3][32][16][512][64] (96 MB)

__device__ __forceinline__ unsigned short f2bf(float f){
  unsigned int u = __float_as_uint(f);
  u += 0x7fffu + ((u >> 16) & 1u);          // RNE
  return (unsigned short)(u >> 16);
}
__device__ __forceinline__ float bfu(unsigned int lo16){
  return __uint_as_float(lo16 << 16);
}

// ---------------- router ----------------

__global__ void meanpool_kernel(const float* __restrict__ x, float* __restrict__ part){
  const int b = blockIdx.x, lc = blockIdx.y, t = threadIdx.x;
  const float* xb = x + ((size_t)b*512 + lc*32)*1024;
  float a0=0.f, a1=0.f, a2=0.f, a3=0.f;
  for (int l = 0; l < 32; ++l){
    const float* row = xb + l*1024;
    a0 += row[t]; a1 += row[t+256]; a2 += row[t+512]; a3 += row[t+768];
  }
  float* o = part + ((size_t)b*16 + lc)*1024;
  o[t] = a0; o[t+256] = a1; o[t+512] = a2; o[t+768] = a3;
}

__global__ void router_kernel(const float* __restrict__ part,
                              const float* __restrict__ rw,
                              const float* __restrict__ rbias,
                              float* __restrict__ probs,
                              int* __restrict__ routes){
  const int b = blockIdx.x, t = threadIdx.x;
  __shared__ float xbar[1024];
  __shared__ float red[256*8];
  #pragma unroll
  for (int k = 0; k < 4; ++k){
    const int d = t + k*256;
    float s = 0.f;
    for (int lc = 0; lc < 16; ++lc) s += part[((size_t)b*16 + lc)*1024 + d];
    xbar[d] = s * (1.0f/512.0f);
  }
  __syncthreads();
  float p[8] = {0.f,0.f,0.f,0.f,0.f,0.f,0.f,0.f};
  #pragma unroll
  for (int k = 0; k < 4; ++k){
    const int d = t + k*256;
    const float xv = xbar[d];
    #pragma unroll
    for (int e = 0; e < 8; ++e) p[e] = fmaf(xv, rw[d*8 + e], p[e]);
  }
  #pragma unroll
  for (int e = 0; e < 8; ++e) red[t*8 + e] = p[e];
  __syncthreads();
  for (int s2 = 128; s2 > 0; s2 >>= 1){
    if (t < s2){
      #pragma unroll
      for (int e = 0; e < 8; ++e) red[t*8 + e] += red[(t + s2)*8 + e];
    }
    __syncthreads();
  }
  if (t == 0){
    float lg[8], mx = -3e38f; int am = 0;
    #pragma unroll
    for (int e = 0; e < 8; ++e){
      lg[e] = red[e] + rbias[e];
      if (lg[e] > mx){ mx = lg[e]; am = e; }   // strict > = first-max, matches argmax
    }
    float sum = 0.f, ex[8];
    #pragma unroll
    for (int e = 0; e < 8; ++e){ ex[e] = __expf(lg[e] - mx); sum += ex[e]; }
    const float inv = 1.0f / sum;
    #pragma unroll
    for (int e = 0; e < 8; ++e) probs[b*8 + e] = ex[e] * inv;
    routes[b] = am;
  }
}

// ---------------- casts ----------------

__global__ void xcast_kernel(const float4* __restrict__ x, unsigned short* __restrict__ xb){
  const size_t i = (size_t)blockIdx.x * blockDim.x + threadIdx.x;
  const float4 v = x[i];
  ushort4 o;
  o.x = f2bf(v.x); o.y = f2bf(v.y); o.z = f2bf(v.z); o.w = f2bf(v.w);
  *(ushort4*)(xb + 4*i) = o;
}

// W [1024][1024] f32 -> Wt bf16 with Wt[e][d] = W[d][e]; one 1024x1024 matrix per blockIdx.z
__global__ void wcast_kernel(const float* __restrict__ W, unsigned short* __restrict__ Wt){
  __shared__ float tile[32][33];
  const int mtx = blockIdx.z;
  const float* Wm = W + (size_t)mtx*1024*1024;
  unsigned short* Wo = Wt + (size_t)mtx*1024*1024;
  const int t = threadIdx.x;
  const int c = t & 31, r0 = t >> 5;
  const int gx = blockIdx.x*32, gy = blockIdx.y*32;   // gx: e tile, gy: d tile
  #pragma unroll
  for (int k = 0; k < 4; ++k){
    const int r = r0 + k*8;
    tile[r][c] = Wm[(size_t)(gy + r)*1024 + gx + c];
  }
  __syncthreads();
  #pragma unroll
  for (int k = 0; k < 4; ++k){
    const int r = r0 + k*8;                            // e-local
    Wo[(size_t)(gx + r)*1024 + gy + c] = f2bf(tile[c][r]);
  }
}

// ---------------- bf16 MFMA GEMM (m97 structure: 128x128 tile, BK=32) ----------------
// MODE 0: A = xb[b], W = Wt[p*8+route]; epilogue RoPE (p<2) -> qkv bf16 [3][B][H][L][hd]
// MODE 1: A = ctx[b], W = Wt_o[route];  epilogue -> d_out fp32 [B][L][1024]

template<int MODE>
__global__ __launch_bounds__(256, 2) void gemm_kernel(
    const unsigned short* __restrict__ A,
    const unsigned short* __restrict__ Wt,
    const int* __restrict__ routes,
    unsigned short* __restrict__ qkvout,
    float* __restrict__ outf)
{
  __shared__ __align__(16) unsigned short As[128*32];
  __shared__ __align__(16) unsigned short Bs[128*32];

  const int z = blockIdx.z;
  const int p = (MODE == 0) ? (z >> 5) : 0;
  const int b = (MODE == 0) ? (z & 31) : z;
  const int route = routes[b];
  const unsigned short* Ab = A + (size_t)b*512*1024;
  const unsigned short* Wb = Wt + (size_t)((MODE == 0) ? (p*8 + route) : route)*1024*1024;
  const int m0 = blockIdx.y * 128;
  const int n0 = blockIdx.x * 128;
  const int t = threadIdx.x;
  const int lane = t & 63;
  const int wave = t >> 6;
  const int wm = (wave >> 1) * 64;
  const int wn = (wave & 1) * 64;
  const int quad = lane >> 4;
  const int ln = lane & 15;

  f32x4 acc[4][4] = {};

  // staging: unit u covers 16B (8 bf16); LDS layout [row][k] row-major, lane-contiguous
  const int u0 = t, u1 = t + 256;
  const unsigned short* gA0 = Ab + (size_t)(m0 + (u0 >> 2))*1024 + (u0 & 3)*8;
  const unsigned short* gA1 = Ab + (size_t)(m0 + (u1 >> 2))*1024 + (u1 & 3)*8;
  const unsigned short* gB0 = Wb + (size_t)(n0 + (u0 >> 2))*1024 + (u0 & 3)*8;
  const unsigned short* gB1 = Wb + (size_t)(n0 + (u1 >> 2))*1024 + (u1 & 3)*8;
  las_t lA0 = (las_t)(As + u0*8), lA1 = (las_t)(As + u1*8);
  las_t lB0 = (las_t)(Bs + u0*8), lB1 = (las_t)(Bs + u1*8);

  const unsigned short* fa[4];
  const unsigned short* fb[4];
  #pragma unroll
  for (int i = 0; i < 4; ++i){
    fa[i] = As + (wm + i*16 + ln)*32 + quad*8;   // A[m][k]: m=lane&15, k=quad*8+j
    fb[i] = Bs + (wn + i*16 + ln)*32 + quad*8;   // B^T[n][k]: n=lane&15
  }

  for (int k0 = 0; k0 < 1024; k0 += 32){
    __syncthreads();
    __builtin_amdgcn_global_load_lds((gas_t)(gA0 + k0), lA0, 16, 0, 0);
    __builtin_amdgcn_global_load_lds((gas_t)(gA1 + k0), lA1, 16, 0, 0);
    __builtin_amdgcn_global_load_lds((gas_t)(gB0 + k0), lB0, 16, 0, 0);
    __builtin_amdgcn_global_load_lds((gas_t)(gB1 + k0), lB1, 16, 0, 0);
    __syncthreads();
    bf16x8 av[4], bv[4];
    #pragma unroll
    for (int i = 0; i < 4; ++i){
      av[i] = *(const bf16x8*)fa[i];
      bv[i] = *(const bf16x8*)fb[i];
    }
    #pragma unroll
    for (int i = 0; i < 4; ++i)
      #pragma unroll
      for (int j = 0; j < 4; ++j)
        acc[i][j] = __builtin_amdgcn_mfma_f32_16x16x32_bf16(av[i], bv[j], acc[i][j], 0, 0, 0);
  }

  // C/D layout: col(n) = lane&15, row(m) = quad*4 + r   [m89/m91-verified]
  if (MODE == 0){
    const bool dorope = (p < 2);
    #pragma unroll
    for (int j = 0; j < 4; ++j){
      const int e  = n0 + wn + j*16 + ln;
      const int h  = e >> 6;
      const int eh = e & 63;
      const float invf = exp2f(-0.41524101f * (float)(eh >> 1)); // 10000^(-2i/64)
      unsigned short* outp = qkvout + ((((size_t)p*32 + b)*16 + h)*512)*64 + eh;
      #pragma unroll
      for (int i = 0; i < 4; ++i){
        #pragma unroll
        for (int r = 0; r < 4; ++r){
          const int l = m0 + wm + i*16 + quad*4 + r;
          const float own = acc[i][j][r];
          float v = own;
          if (dorope){
            const float par = __shfl_xor(own, 1, 64);  // pair lane holds e^1 (same row)
            float sn, cs;
            __sincosf((float)l * invf, &sn, &cs);
            v = (e & 1) ? fmaf(own, cs, par*sn) : fmaf(own, cs, -par*sn);
          }
          outp[(size_t)l*64] = f2bf(v);
        }
      }
    }
  } else {
    #pragma unroll
    for (int j = 0; j < 4; ++j){
      const int e = n0 + wn + j*16 + ln;
      #pragma unroll
      for (int i = 0; i < 4; ++i){
        #pragma unroll
        for (int r = 0; r < 4; ++r){
          const int l = m0 + wm + i*16 + quad*4 + r;
          outf[((size_t)b*512 + l)*1024 + e] = acc[i][j][r];
        }
      }
    }
  }
}

// ---------------- fp32 flash attention, 64x64 tiles ----------------

__global__ __launch_bounds__(256, 2) void attn_kernel(
    const unsigned short* __restrict__ qkv,
    unsigned short* __restrict__ ctx)
{
  __shared__ __align__(16) float Qt[64][68];   // [d][r] transposed
  __shared__ __align__(16) float Kt[64][68];   // [d][c] transposed
  __shared__ float Ss[64][65];                 // S/P tile [r][c] (scalar access only)
  __shared__ __align__(16) unsigned short Vsb[64*64]; // V bf16 [c][d]
  __shared__ float mrow[64], lrow[64], arow[64];

  const int qt = blockIdx.x, h = blockIdx.y, b = blockIdx.z;
  const size_t HO = (((size_t)b)*16 + h)*512*64;
  const size_t PS = (size_t)32*16*512*64;
  const unsigned short* Qg = qkv + HO;
  const unsigned short* Kg = qkv + PS + HO;
  const unsigned short* Vg = qkv + 2*PS + HO;

  const int t  = threadIdx.x;
  const int rb = (t >> 4) << 2;   // 4 query rows owned
  const int cb = (t & 15) << 2;   // 4 cols (S) / 4 dims (O)
  const int lr = t >> 2;          // load row
  const int d0 = (t & 3) << 4;    // load dim base (16 elems)

  if (t < 64){ mrow[t] = -3e38f; lrow[t] = 0.0f; }

  {
    const unsigned short* src = Qg + ((size_t)(qt*64 + lr))*64 + d0;
    const uint4 u = *(const uint4*)src;
    const uint4 w = *(const uint4*)(src + 8);
    Qt[d0+ 0][lr]=bfu(u.x&0xffffu); Qt[d0+ 1][lr]=bfu(u.x>>16);
    Qt[d0+ 2][lr]=bfu(u.y&0xffffu); Qt[d0+ 3][lr]=bfu(u.y>>16);
    Qt[d0+ 4][lr]=bfu(u.z&0xffffu); Qt[d0+ 5][lr]=bfu(u.z>>16);
    Qt[d0+ 6][lr]=bfu(u.w&0xffffu); Qt[d0+ 7][lr]=bfu(u.w>>16);
    Qt[d0+ 8][lr]=bfu(w.x&0xffffu); Qt[d0+ 9][lr]=bfu(w.x>>16);
    Qt[d0+10][lr]=bfu(w.y&0xffffu); Qt[d0+11][lr]=bfu(w.y>>16);
    Qt[d0+12][lr]=bfu(w.z&0xffffu); Qt[d0+13][lr]=bfu(w.z>>16);
    Qt[d0+14][lr]=bfu(w.w&0xffffu); Qt[d0+15][lr]=bfu(w.w>>16);
  }
  __syncthreads();

  float Ob[4][4] = {};

  for (int kt = 0; kt <= qt; ++kt){
    {
      const unsigned short* ks = Kg + ((size_t)(kt*64 + lr))*64 + d0;
      const uint4 u = *(const uint4*)ks;
      const uint4 w = *(const uint4*)(ks + 8);
      Kt[d0+ 0][lr]=bfu(u.x&0xffffu); Kt[d0+ 1][lr]=bfu(u.x>>16);
      Kt[d0+ 2][lr]=bfu(u.y&0xffffu); Kt[d0+ 3][lr]=bfu(u.y>>16);
      Kt[d0+ 4][lr]=bfu(u.z&0xffffu); Kt[d0+ 5][lr]=bfu(u.z>>16);
      Kt[d0+ 6][lr]=bfu(u.w&0xffffu); Kt[d0+ 7][lr]=bfu(u.w>>16);
      Kt[d0+ 8][lr]=bfu(w.x&0xffffu); Kt[d0+ 9][lr]=bfu(w.x>>16);
      Kt[d0+10][lr]=bfu(w.y&0xffffu); Kt[d0+11][lr]=bfu(w.y>>16);
      Kt[d0+12][lr]=bfu(w.z&0xffffu); Kt[d0+13][lr]=bfu(w.z>>16);
      Kt[d0+14][lr]=bfu(w.w&0xffffu); Kt[d0+15][lr]=bfu(w.w>>16);
      const unsigned short* vs = Vg + ((size_t)(kt*64 + lr))*64 + d0;
      *(uint4*)&Vsb[lr*64 + d0]     = *(const uint4*)vs;       // raw bf16 copy
      *(uint4*)&Vsb[lr*64 + d0 + 8] = *(const uint4*)(vs + 8);
    }
    __syncthreads();

    // S = Q K^T
    float s[4][4] = {};
    #pragma unroll 4
    for (int d = 0; d < 64; ++d){
      const float4 qv = *(const float4*)&Qt[d][rb];
      const float4 kv = *(const float4*)&Kt[d][cb];
      const float qa[4] = {qv.x, qv.y, qv.z, qv.w};
      const float ka[4] = {kv.x, kv.y, kv.z, kv.w};
      #pragma unroll
      for (int i = 0; i < 4; ++i)
        #pragma unroll
        for (int j = 0; j < 4; ++j)
          s[i][j] = fmaf(qa[i], ka[j], s[i][j]);
    }
    const bool diag = (kt == qt);
    #pragma unroll
    for (int i = 0; i < 4; ++i)
      #pragma unroll
      for (int j = 0; j < 4; ++j){
        float v = s[i][j] * 0.125f;
        if (diag && (cb + j > rb + i)) v = -1e9f;
        Ss[rb+i][cb+j] = v;
      }
    __syncthreads();

    // online softmax row stats (threads 0..63, one row each)
    if (t < 64){
      const int r = t;
      const float m_old = mrow[r];
      float mx = m_old;
      #pragma unroll 8
      for (int c = 0; c < 64; ++c) mx = fmaxf(mx, Ss[r][c]);
      float sum = 0.f;
      #pragma unroll 8
      for (int c = 0; c < 64; ++c){
        const float pv = __expf(Ss[r][c] - mx);
        Ss[r][c] = pv;
        sum += pv;
      }
      const float alpha = __expf(m_old - mx);
      mrow[r] = mx;
      lrow[r] = lrow[r]*alpha + sum;
      arow[r] = alpha;
    }
    __syncthreads();

    const float al[4] = {arow[rb], arow[rb+1], arow[rb+2], arow[rb+3]};
    #pragma unroll
    for (int i = 0; i < 4; ++i)
      #pragma unroll
      for (int j = 0; j < 4; ++j)
        Ob[i][j] *= al[i];

    // O += P V
    #pragma unroll 2
    for (int kc = 0; kc < 64; ++kc){
      const uint2 vv = *(const uint2*)&Vsb[kc*64 + cb];
      const float va[4] = {bfu(vv.x & 0xffffu), bfu(vv.x >> 16),
                           bfu(vv.y & 0xffffu), bfu(vv.y >> 16)};
      const float pa[4] = {Ss[rb+0][kc], Ss[rb+1][kc], Ss[rb+2][kc], Ss[rb+3][kc]};
      #pragma unroll
      for (int i = 0; i < 4; ++i)
        #pragma unroll
        for (int j = 0; j < 4; ++j)
          Ob[i][j] = fmaf(pa[i], va[j], Ob[i][j]);
    }
    __syncthreads();
  }

  const float li[4] = {1.f/lrow[rb], 1.f/lrow[rb+1], 1.f/lrow[rb+2], 1.f/lrow[rb+3]};
  #pragma unroll
  for (int i = 0; i < 4; ++i){
    const int l = qt*64 + rb + i;
    unsigned short* op = ctx + ((size_t)b*512 + l)*1024 + h*64 + cb;
    #pragma unroll
    for (int j = 0; j < 4; ++j)
      op[j] = f2bf(Ob[i][j] * li[i]);
  }
}

// ---------------- launch ----------------

extern "C" void kernel_launch(void* const* d_in, const int* in_sizes, int n_in,
                              void* d_out, int out_size, void* d_ws, size_t ws_size,
                              hipStream_t stream) {
  const float* x     = (const float*)d_in[0];
  const float* qw    = (const float*)d_in[1];
  const float* kw    = (const float*)d_in[2];
  const float* vw    = (const float*)d_in[3];
  const float* ow    = (const float*)d_in[4];
  const float* rw    = (const float*)d_in[5];
  const float* rbias = (const float*)d_in[6];
  float* out = (float*)d_out;
  char* ws = (char*)d_ws;

  float* part            = (float*)(ws + OFF_PART);
  int* routes            = (int*)(ws + OFF_ROUTES);
  unsigned short* xb     = (unsigned short*)(ws + OFF_XB);
  unsigned short* wt     = (unsigned short*)(ws + OFF_WT);
  unsigned short* qkvbuf = (unsigned short*)(ws + OFF_QKV);
  unsigned short* ctx    = xb;   // xb fully consumed by gemm<0> before attention writes ctx
  float* probs = out + (size_t)32*512*1024;

  meanpool_kernel<<<dim3(32, 16), 256, 0, stream>>>(x, part);
  router_kernel<<<32, 256, 0, stream>>>(part, rw, rbias, probs, routes);
  xcast_kernel<<<16384, 256, 0, stream>>>((const float4*)x, xb);
  wcast_kernel<<<dim3(32, 32, 8), 256, 0, stream>>>(qw, wt);
  wcast_kernel<<<dim3(32, 32, 8), 256, 0, stream>>>(kw, wt + (size_t)8*1024*1024);
  wcast_kernel<<<dim3(32, 32, 8), 256, 0, stream>>>(vw, wt + (size_t)16*1024*1024);
  wcast_kernel<<<dim3(32, 32, 8), 256, 0, stream>>>(ow, wt + (size_t)24*1024*1024);
  gemm_kernel<0><<<dim3(8, 4, 96), 256, 0, stream>>>(xb, wt, routes, qkvbuf, nullptr);
  attn_kernel<<<dim3(8, 16, 32), 256, 0, stream>>>(qkvbuf, ctx);
  gemm_kernel<1><<<dim3(8, 4, 32), 256, 0, stream>>>(ctx, wt + (size_t)24*1024*1024, routes,
                                                     nullptr, out);
}

// Round 3
// 616.889 us; speedup vs baseline: 2.0191x; 2.0191x over previous
//
#include <hip/hip_runtime.h>

// RoutedSelfAttention on MI355X.
// Pipeline: meanpool -> router -> cast x (bf16) -> transpose-cast W (bf16, W^T)
//           -> MFMA GEMM qkv (+fused RoPE) -> bf16 MFMA flash attention -> MFMA GEMM out proj.

typedef __attribute__((ext_vector_type(8))) short bf16x8;   // 8 bf16 = 4 VGPR (A/B frag)
typedef __attribute__((ext_vector_type(4))) float f32x4;    // C/D frag
typedef __attribute__((ext_vector_type(8))) unsigned short u16x8;

typedef const __attribute__((address_space(1))) unsigned short* gas_t;
typedef __attribute__((address_space(3))) unsigned short* las_t;

#define OFF_PART   (0ull)            // [32][16][1024] f32 partial mean sums (2 MB)
#define OFF_ROUTES (2ull << 20)      // [32] int
#define OFF_XB     (3ull << 20)      // x bf16 [32][512][1024] (32 MB); reused as ctx after gemm<0>
#define OFF_WT     (40ull << 20)     // W^T bf16 [4][8][1024][1024] (64 MB)
#define OFF_QKV    (112ull << 20)    // q,k,v bf16 [3][32][16][512][64] (96 MB)

__device__ __forceinline__ unsigned short f2bf(float f){
  unsigned int u = __float_as_uint(f);
  u += 0x7fffu + ((u >> 16) & 1u);          // RNE
  return (unsigned short)(u >> 16);
}
__device__ __forceinline__ float bfu(unsigned int lo16){
  return __uint_as_float(lo16 << 16);
}

// ---------------- router ----------------

__global__ void meanpool_kernel(const float* __restrict__ x, float* __restrict__ part){
  const int b = blockIdx.x, lc = blockIdx.y, t = threadIdx.x;
  const float* xb = x + ((size_t)b*512 + lc*32)*1024;
  float a0=0.f, a1=0.f, a2=0.f, a3=0.f;
  for (int l = 0; l < 32; ++l){
    const float* row = xb + l*1024;
    a0 += row[t]; a1 += row[t+256]; a2 += row[t+512]; a3 += row[t+768];
  }
  float* o = part + ((size_t)b*16 + lc)*1024;
  o[t] = a0; o[t+256] = a1; o[t+512] = a2; o[t+768] = a3;
}

__global__ void router_kernel(const float* __restrict__ part,
                              const float* __restrict__ rw,
                              const float* __restrict__ rbias,
                              float* __restrict__ probs,
                              int* __restrict__ routes){
  const int b = blockIdx.x, t = threadIdx.x;
  __shared__ float xbar[1024];
  __shared__ float red[256*8];
  #pragma unroll
  for (int k = 0; k < 4; ++k){
    const int d = t + k*256;
    float s = 0.f;
    for (int lc = 0; lc < 16; ++lc) s += part[((size_t)b*16 + lc)*1024 + d];
    xbar[d] = s * (1.0f/512.0f);
  }
  __syncthreads();
  float p[8] = {0.f,0.f,0.f,0.f,0.f,0.f,0.f,0.f};
  #pragma unroll
  for (int k = 0; k < 4; ++k){
    const int d = t + k*256;
    const float xv = xbar[d];
    #pragma unroll
    for (int e = 0; e < 8; ++e) p[e] = fmaf(xv, rw[d*8 + e], p[e]);
  }
  #pragma unroll
  for (int e = 0; e < 8; ++e) red[t*8 + e] = p[e];
  __syncthreads();
  for (int s2 = 128; s2 > 0; s2 >>= 1){
    if (t < s2){
      #pragma unroll
      for (int e = 0; e < 8; ++e) red[t*8 + e] += red[(t + s2)*8 + e];
    }
    __syncthreads();
  }
  if (t == 0){
    float lg[8], mx = -3e38f; int am = 0;
    #pragma unroll
    for (int e = 0; e < 8; ++e){
      lg[e] = red[e] + rbias[e];
      if (lg[e] > mx){ mx = lg[e]; am = e; }
    }
    float sum = 0.f, ex[8];
    #pragma unroll
    for (int e = 0; e < 8; ++e){ ex[e] = __expf(lg[e] - mx); sum += ex[e]; }
    const float inv = 1.0f / sum;
    #pragma unroll
    for (int e = 0; e < 8; ++e) probs[b*8 + e] = ex[e] * inv;
    routes[b] = am;
  }
}

// ---------------- casts ----------------

__global__ void xcast_kernel(const float4* __restrict__ x, unsigned short* __restrict__ xb){
  const size_t i = (size_t)blockIdx.x * blockDim.x + threadIdx.x;
  const float4 v = x[i];
  ushort4 o;
  o.x = f2bf(v.x); o.y = f2bf(v.y); o.z = f2bf(v.z); o.w = f2bf(v.w);
  *(ushort4*)(xb + 4*i) = o;
}

// W [1024][1024] f32 -> Wt bf16 with Wt[e][d] = W[d][e]
__global__ void wcast_kernel(const float* __restrict__ W, unsigned short* __restrict__ Wt){
  __shared__ float tile[32][33];
  const int mtx = blockIdx.z;
  const float* Wm = W + (size_t)mtx*1024*1024;
  unsigned short* Wo = Wt + (size_t)mtx*1024*1024;
  const int t = threadIdx.x;
  const int c = t & 31, r0 = t >> 5;
  const int gx = blockIdx.x*32, gy = blockIdx.y*32;
  #pragma unroll
  for (int k = 0; k < 4; ++k){
    const int r = r0 + k*8;
    tile[r][c] = Wm[(size_t)(gy + r)*1024 + gx + c];
  }
  __syncthreads();
  #pragma unroll
  for (int k = 0; k < 4; ++k){
    const int r = r0 + k*8;
    Wo[(size_t)(gx + r)*1024 + gy + c] = f2bf(tile[c][r]);
  }
}

// ---------------- bf16 MFMA GEMM (m97 structure: 128x128 tile, BK=32) ----------------

template<int MODE>
__global__ __launch_bounds__(256, 2) void gemm_kernel(
    const unsigned short* __restrict__ A,
    const unsigned short* __restrict__ Wt,
    const int* __restrict__ routes,
    unsigned short* __restrict__ qkvout,
    float* __restrict__ outf)
{
  __shared__ __align__(16) unsigned short As[128*32];
  __shared__ __align__(16) unsigned short Bs[128*32];

  const int z = blockIdx.z;
  const int p = (MODE == 0) ? (z >> 5) : 0;
  const int b = (MODE == 0) ? (z & 31) : z;
  const int route = routes[b];
  const unsigned short* Ab = A + (size_t)b*512*1024;
  const unsigned short* Wb = Wt + (size_t)((MODE == 0) ? (p*8 + route) : route)*1024*1024;
  const int m0 = blockIdx.y * 128;
  const int n0 = blockIdx.x * 128;
  const int t = threadIdx.x;
  const int lane = t & 63;
  const int wave = t >> 6;
  const int wm = (wave >> 1) * 64;
  const int wn = (wave & 1) * 64;
  const int quad = lane >> 4;
  const int ln = lane & 15;

  f32x4 acc[4][4] = {};

  const int u0 = t, u1 = t + 256;
  const unsigned short* gA0 = Ab + (size_t)(m0 + (u0 >> 2))*1024 + (u0 & 3)*8;
  const unsigned short* gA1 = Ab + (size_t)(m0 + (u1 >> 2))*1024 + (u1 & 3)*8;
  const unsigned short* gB0 = Wb + (size_t)(n0 + (u0 >> 2))*1024 + (u0 & 3)*8;
  const unsigned short* gB1 = Wb + (size_t)(n0 + (u1 >> 2))*1024 + (u1 & 3)*8;
  las_t lA0 = (las_t)(As + u0*8), lA1 = (las_t)(As + u1*8);
  las_t lB0 = (las_t)(Bs + u0*8), lB1 = (las_t)(Bs + u1*8);

  const unsigned short* fa[4];
  const unsigned short* fb[4];
  #pragma unroll
  for (int i = 0; i < 4; ++i){
    fa[i] = As + (wm + i*16 + ln)*32 + quad*8;
    fb[i] = Bs + (wn + i*16 + ln)*32 + quad*8;
  }

  for (int k0 = 0; k0 < 1024; k0 += 32){
    __syncthreads();
    __builtin_amdgcn_global_load_lds((gas_t)(gA0 + k0), lA0, 16, 0, 0);
    __builtin_amdgcn_global_load_lds((gas_t)(gA1 + k0), lA1, 16, 0, 0);
    __builtin_amdgcn_global_load_lds((gas_t)(gB0 + k0), lB0, 16, 0, 0);
    __builtin_amdgcn_global_load_lds((gas_t)(gB1 + k0), lB1, 16, 0, 0);
    __syncthreads();
    bf16x8 av[4], bv[4];
    #pragma unroll
    for (int i = 0; i < 4; ++i){
      av[i] = *(const bf16x8*)fa[i];
      bv[i] = *(const bf16x8*)fb[i];
    }
    #pragma unroll
    for (int i = 0; i < 4; ++i)
      #pragma unroll
      for (int j = 0; j < 4; ++j)
        acc[i][j] = __builtin_amdgcn_mfma_f32_16x16x32_bf16(av[i], bv[j], acc[i][j], 0, 0, 0);
  }

  if (MODE == 0){
    const bool dorope = (p < 2);
    #pragma unroll
    for (int j = 0; j < 4; ++j){
      const int e  = n0 + wn + j*16 + ln;
      const int h  = e >> 6;
      const int eh = e & 63;
      const float invf = exp2f(-0.41524101f * (float)(eh >> 1)); // 10000^(-2i/64)
      unsigned short* outp = qkvout + ((((size_t)p*32 + b)*16 + h)*512)*64 + eh;
      #pragma unroll
      for (int i = 0; i < 4; ++i){
        #pragma unroll
        for (int r = 0; r < 4; ++r){
          const int l = m0 + wm + i*16 + quad*4 + r;
          const float own = acc[i][j][r];
          float v = own;
          if (dorope){
            const float par = __shfl_xor(own, 1, 64);
            float sn, cs;
            __sincosf((float)l * invf, &sn, &cs);
            v = (e & 1) ? fmaf(own, cs, par*sn) : fmaf(own, cs, -par*sn);
          }
          outp[(size_t)l*64] = f2bf(v);
        }
      }
    }
  } else {
    #pragma unroll
    for (int j = 0; j < 4; ++j){
      const int e = n0 + wn + j*16 + ln;
      #pragma unroll
      for (int i = 0; i < 4; ++i){
        #pragma unroll
        for (int r = 0; r < 4; ++r){
          const int l = m0 + wm + i*16 + quad*4 + r;
          outf[((size_t)b*512 + l)*1024 + e] = acc[i][j][r];
        }
      }
    }
  }
}

// ---------------- bf16 MFMA flash attention, 64x64 tiles ----------------
// Block = (qt, h, b): 64 Q-rows, 4 waves x 16 rows. Per K-tile:
//   S = Q K^T (MFMA, K [key][d] = B^T layout), online softmax in registers
//   (C-layout rows = quad*4+r; butterfly over ln lanes), P -> LDS (stride 72)
//   C-layout -> A-layout, PV via V^T in LDS (pack-transposed, 2-way-conflict writes).

#define PSTR 72

__global__ __launch_bounds__(256, 2) void attn_kernel(
    const unsigned short* __restrict__ qkv,
    unsigned short* __restrict__ ctx)
{
  __shared__ __align__(16) unsigned short Qs[64*64];
  __shared__ __align__(16) unsigned short Ks[64*64];
  __shared__ __align__(16) unsigned short Vt[64*64];   // V^T [d][key]
  __shared__ __align__(16) unsigned short Ps[64*PSTR];

  const int qt = blockIdx.x, h = blockIdx.y, b = blockIdx.z;
  const size_t HO  = (((size_t)b)*16 + h)*512*64;
  const size_t PSZ = (size_t)32*16*512*64;
  const unsigned short* Qg = qkv + HO + (size_t)qt*4096;
  const unsigned short* Kg = qkv + PSZ + HO;
  const unsigned short* Vg = qkv + 2*PSZ + HO;

  const int t    = threadIdx.x;
  const int lane = t & 63;
  const int wave = t >> 6;
  const int quad = lane >> 4;
  const int ln   = lane & 15;
  const int wq   = wave * 16;

  // Q stage: tile is 8192 contiguous bytes
  __builtin_amdgcn_global_load_lds((gas_t)(Qg + t*8),       (las_t)(Qs + t*8),       16, 0, 0);
  __builtin_amdgcn_global_load_lds((gas_t)(Qg + (t+256)*8), (las_t)(Qs + (t+256)*8), 16, 0, 0);

  // V transpose assignment: thread packs rows (2*va, 2*va+1), dims vg*8..+7
  const int va = t & 31;
  const int vg = t >> 5;
  unsigned int* Vt32 = (unsigned int*)Vt;

  float m_r[4], l_r[4];
  #pragma unroll
  for (int r = 0; r < 4; ++r){ m_r[r] = -3e38f; l_r[r] = 0.f; }
  f32x4 o[4] = {};

  const unsigned short* aQ = Qs + (wq + ln)*64 + quad*8;
  const unsigned short* bK = Ks + ln*64 + quad*8;
  const unsigned short* aP = Ps + (wq + ln)*PSTR + quad*8;
  const unsigned short* bV = Vt + ln*64 + quad*8;

  for (int kt = 0; kt <= qt; ++kt){
    __syncthreads();   // prior-iter reads of Ks/Vt complete
    const unsigned short* Ktile = Kg + kt*4096;
    __builtin_amdgcn_global_load_lds((gas_t)(Ktile + t*8),       (las_t)(Ks + t*8),       16, 0, 0);
    __builtin_amdgcn_global_load_lds((gas_t)(Ktile + (t+256)*8), (las_t)(Ks + (t+256)*8), 16, 0, 0);
    {
      const unsigned short* vb = Vg + kt*4096 + (2*va)*64 + vg*8;
      const u16x8 r0 = *(const u16x8*)vb;
      const u16x8 r1 = *(const u16x8*)(vb + 64);
      #pragma unroll
      for (int i = 0; i < 8; ++i)
        Vt32[(vg*8 + i)*32 + va] = (unsigned int)r0[i] | ((unsigned int)r1[i] << 16);
    }
    __syncthreads();   // K/V ready (barrier drains vmcnt)

    // S = Q K^T  (16x64 per wave)
    f32x4 s[4] = {};
    #pragma unroll
    for (int ks = 0; ks < 2; ++ks){
      const bf16x8 aq = *(const bf16x8*)(aQ + ks*32);
      #pragma unroll
      for (int kn = 0; kn < 4; ++kn){
        const bf16x8 bk = *(const bf16x8*)(bK + kn*1024 + ks*32);
        s[kn] = __builtin_amdgcn_mfma_f32_16x16x32_bf16(aq, bk, s[kn], 0, 0, 0);
      }
    }

    // scale + causal mask + online softmax
    const bool diag = (kt == qt);
    float p[4][4], lm[4];
    #pragma unroll
    for (int r = 0; r < 4; ++r) lm[r] = -3e38f;
    #pragma unroll
    for (int kn = 0; kn < 4; ++kn){
      const int col = kn*16 + ln;
      #pragma unroll
      for (int r = 0; r < 4; ++r){
        float v = s[kn][r] * 0.125f;
        if (diag && col > wq + quad*4 + r) v = -1e9f;
        p[kn][r] = v;
        lm[r] = fmaxf(lm[r], v);
      }
    }
    #pragma unroll
    for (int off = 1; off < 16; off <<= 1)
      #pragma unroll
      for (int r = 0; r < 4; ++r)
        lm[r] = fmaxf(lm[r], __shfl_xor(lm[r], off, 64));
    float alpha[4], rsum[4];
    #pragma unroll
    for (int r = 0; r < 4; ++r){
      const float mn = fmaxf(m_r[r], lm[r]);
      alpha[r] = __expf(m_r[r] - mn);
      m_r[r] = mn;
    }
    #pragma unroll
    for (int kn = 0; kn < 4; ++kn)
      #pragma unroll
      for (int r = 0; r < 4; ++r)
        p[kn][r] = __expf(p[kn][r] - m_r[r]);
    #pragma unroll
    for (int r = 0; r < 4; ++r)
      rsum[r] = (p[0][r] + p[1][r]) + (p[2][r] + p[3][r]);
    #pragma unroll
    for (int off = 1; off < 16; off <<= 1)
      #pragma unroll
      for (int r = 0; r < 4; ++r)
        rsum[r] += __shfl_xor(rsum[r], off, 64);
    #pragma unroll
    for (int r = 0; r < 4; ++r) l_r[r] = l_r[r]*alpha[r] + rsum[r];
    #pragma unroll
    for (int dn = 0; dn < 4; ++dn)
      #pragma unroll
      for (int r = 0; r < 4; ++r)
        o[dn][r] *= alpha[r];

    // P: C-layout -> LDS [qrow][key] (A-layout source), own rows only
    #pragma unroll
    for (int kn = 0; kn < 4; ++kn)
      #pragma unroll
      for (int r = 0; r < 4; ++r)
        Ps[(wq + quad*4 + r)*PSTR + kn*16 + ln] = f2bf(p[kn][r]);

    // O += P V  (wave-local Ps round-trip; no barrier needed)
    #pragma unroll
    for (int ks = 0; ks < 2; ++ks){
      const bf16x8 ap = *(const bf16x8*)(aP + ks*32);
      #pragma unroll
      for (int dn = 0; dn < 4; ++dn){
        const bf16x8 bv = *(const bf16x8*)(bV + dn*1024 + ks*32);
        o[dn] = __builtin_amdgcn_mfma_f32_16x16x32_bf16(ap, bv, o[dn], 0, 0, 0);
      }
    }
  }

  // epilogue: O /= l, write ctx [b][l][h*64+d]
  #pragma unroll
  for (int r = 0; r < 4; ++r){
    const float inv = 1.0f / l_r[r];
    unsigned short* op = ctx + ((size_t)b*512 + qt*64 + wq + quad*4 + r)*1024 + h*64 + ln;
    #pragma unroll
    for (int dn = 0; dn < 4; ++dn)
      op[dn*16] = f2bf(o[dn][r] * inv);
  }
}

// ---------------- launch ----------------

extern "C" void kernel_launch(void* const* d_in, const int* in_sizes, int n_in,
                              void* d_out, int out_size, void* d_ws, size_t ws_size,
                              hipStream_t stream) {
  const float* x     = (const float*)d_in[0];
  const float* qw    = (const float*)d_in[1];
  const float* kw    = (const float*)d_in[2];
  const float* vw    = (const float*)d_in[3];
  const float* ow    = (const float*)d_in[4];
  const float* rw    = (const float*)d_in[5];
  const float* rbias = (const float*)d_in[6];
  float* out = (float*)d_out;
  char* ws = (char*)d_ws;

  float* part            = (float*)(ws + OFF_PART);
  int* routes            = (int*)(ws + OFF_ROUTES);
  unsigned short* xb     = (unsigned short*)(ws + OFF_XB);
  unsigned short* wt     = (unsigned short*)(ws + OFF_WT);
  unsigned short* qkvbuf = (unsigned short*)(ws + OFF_QKV);
  unsigned short* ctx    = xb;
  float* probs = out + (size_t)32*512*1024;

  meanpool_kernel<<<dim3(32, 16), 256, 0, stream>>>(x, part);
  router_kernel<<<32, 256, 0, stream>>>(part, rw, rbias, probs, routes);
  xcast_kernel<<<16384, 256, 0, stream>>>((const float4*)x, xb);
  wcast_kernel<<<dim3(32, 32, 8), 256, 0, stream>>>(qw, wt);
  wcast_kernel<<<dim3(32, 32, 8), 256, 0, stream>>>(kw, wt + (size_t)8*1024*1024);
  wcast_kernel<<<dim3(32, 32, 8), 256, 0, stream>>>(vw, wt + (size_t)16*1024*1024);
  wcast_kernel<<<dim3(32, 32, 8), 256, 0, stream>>>(ow, wt + (size_t)24*1024*1024);
  gemm_kernel<0><<<dim3(8, 4, 96), 256, 0, stream>>>(xb, wt, routes, qkvbuf, nullptr);
  attn_kernel<<<dim3(8, 16, 32), 256, 0, stream>>>(qkvbuf, ctx);
  gemm_kernel<1><<<dim3(8, 4, 32), 256, 0, stream>>>(ctx, wt + (size_t)24*1024*1024, routes,
                                                     nullptr, out);
}

// Round 4
// 560.804 us; speedup vs baseline: 2.2210x; 1.1000x over previous
//
#include <hip/hip_runtime.h>

// RoutedSelfAttention on MI355X.
// meanpool+cast -> router -> wcast (W^T bf16) -> MFMA GEMM qkv (+RoPE, v written transposed)
// -> bf16 MFMA flash attention (128-row Q tiles, dbuf K/vT, xor-swizzled LDS) -> MFMA GEMM out.

typedef __attribute__((ext_vector_type(8))) short bf16x8;
typedef __attribute__((ext_vector_type(4))) float f32x4;

typedef const __attribute__((address_space(1))) unsigned short* gas_t;
typedef __attribute__((address_space(3))) unsigned short* las_t;

#define OFF_PART   (0ull)            // [32][16][1024] f32 partial mean sums (2 MB)
#define OFF_ROUTES (2ull << 20)      // [32] int
#define OFF_XB     (3ull << 20)      // x bf16 [32][512][1024] (32 MB); reused as ctx
#define OFF_WT     (40ull << 20)     // W^T bf16 [4][8][1024][1024] (64 MB)
#define OFF_QKV    (112ull << 20)    // q,k [p][32][16][512][64]; vT [32][16][64][512] (96 MB)

__device__ __forceinline__ unsigned short f2bf(float f){
  unsigned int u = __float_as_uint(f);
  u += 0x7fffu + ((u >> 16) & 1u);          // RNE
  return (unsigned short)(u >> 16);
}

// ---------------- router (meanpool fused with bf16 cast) ----------------

__global__ void meanpool_kernel(const float* __restrict__ x, float* __restrict__ part,
                                unsigned short* __restrict__ xb){
  const int b = blockIdx.x, lc = blockIdx.y, t = threadIdx.x;
  const size_t base = ((size_t)b*512 + lc*32)*1024;
  const float* xs = x + base;
  unsigned short* xo = xb + base;
  float a0=0.f, a1=0.f, a2=0.f, a3=0.f;
  for (int l = 0; l < 32; ++l){
    const float* row = xs + l*1024;
    unsigned short* orow = xo + l*1024;
    const float v0 = row[t], v1 = row[t+256], v2 = row[t+512], v3 = row[t+768];
    a0 += v0; a1 += v1; a2 += v2; a3 += v3;
    orow[t] = f2bf(v0); orow[t+256] = f2bf(v1); orow[t+512] = f2bf(v2); orow[t+768] = f2bf(v3);
  }
  float* o = part + ((size_t)b*16 + lc)*1024;
  o[t] = a0; o[t+256] = a1; o[t+512] = a2; o[t+768] = a3;
}

__global__ void router_kernel(const float* __restrict__ part,
                              const float* __restrict__ rw,
                              const float* __restrict__ rbias,
                              float* __restrict__ probs,
                              int* __restrict__ routes){
  const int b = blockIdx.x, t = threadIdx.x;
  __shared__ float xbar[1024];
  __shared__ float red[256*8];
  #pragma unroll
  for (int k = 0; k < 4; ++k){
    const int d = t + k*256;
    float s = 0.f;
    for (int lc = 0; lc < 16; ++lc) s += part[((size_t)b*16 + lc)*1024 + d];
    xbar[d] = s * (1.0f/512.0f);
  }
  __syncthreads();
  float p[8] = {0.f,0.f,0.f,0.f,0.f,0.f,0.f,0.f};
  #pragma unroll
  for (int k = 0; k < 4; ++k){
    const int d = t + k*256;
    const float xv = xbar[d];
    #pragma unroll
    for (int e = 0; e < 8; ++e) p[e] = fmaf(xv, rw[d*8 + e], p[e]);
  }
  #pragma unroll
  for (int e = 0; e < 8; ++e) red[t*8 + e] = p[e];
  __syncthreads();
  for (int s2 = 128; s2 > 0; s2 >>= 1){
    if (t < s2){
      #pragma unroll
      for (int e = 0; e < 8; ++e) red[t*8 + e] += red[(t + s2)*8 + e];
    }
    __syncthreads();
  }
  if (t == 0){
    float lg[8], mx = -3e38f; int am = 0;
    #pragma unroll
    for (int e = 0; e < 8; ++e){
      lg[e] = red[e] + rbias[e];
      if (lg[e] > mx){ mx = lg[e]; am = e; }
    }
    float sum = 0.f, ex[8];
    #pragma unroll
    for (int e = 0; e < 8; ++e){ ex[e] = __expf(lg[e] - mx); sum += ex[e]; }
    const float inv = 1.0f / sum;
    #pragma unroll
    for (int e = 0; e < 8; ++e) probs[b*8 + e] = ex[e] * inv;
    routes[b] = am;
  }
}

// ---------------- weight transpose-cast ----------------

__global__ void wcast_kernel(const float* __restrict__ W, unsigned short* __restrict__ Wt){
  __shared__ float tile[32][33];
  const int mtx = blockIdx.z;
  const float* Wm = W + (size_t)mtx*1024*1024;
  unsigned short* Wo = Wt + (size_t)mtx*1024*1024;
  const int t = threadIdx.x;
  const int c = t & 31, r0 = t >> 5;
  const int gx = blockIdx.x*32, gy = blockIdx.y*32;
  #pragma unroll
  for (int k = 0; k < 4; ++k){
    const int r = r0 + k*8;
    tile[r][c] = Wm[(size_t)(gy + r)*1024 + gx + c];
  }
  __syncthreads();
  #pragma unroll
  for (int k = 0; k < 4; ++k){
    const int r = r0 + k*8;
    Wo[(size_t)(gx + r)*1024 + gy + c] = f2bf(tile[c][r]);
  }
}

// ---------------- bf16 MFMA GEMM (128x128 tile, BK=32, xor-swizzled LDS) ----------------
// MODE 0: A=xb[b], W=Wt[p*8+route]; p<2: RoPE -> q/k [p][b][h][l][d]; p==2: vT [b][h][d][l]
// MODE 1: A=ctx[b], W=Wt_o[route]; -> d_out fp32

template<int MODE>
__global__ __launch_bounds__(256, 2) void gemm_kernel(
    const unsigned short* __restrict__ A,
    const unsigned short* __restrict__ Wt,
    const int* __restrict__ routes,
    unsigned short* __restrict__ qkvout,
    float* __restrict__ outf)
{
  __shared__ __align__(16) unsigned short As[128*32];
  __shared__ __align__(16) unsigned short Bs[128*32];

  const int z = blockIdx.z;
  const int p = (MODE == 0) ? (z >> 5) : 0;
  const int b = (MODE == 0) ? (z & 31) : z;
  const int route = routes[b];
  const unsigned short* Ab = A + (size_t)b*512*1024;
  const unsigned short* Wb = Wt + (size_t)((MODE == 0) ? (p*8 + route) : route)*1024*1024;
  const int m0 = blockIdx.y * 128;
  const int n0 = blockIdx.x * 128;
  const int t = threadIdx.x;
  const int lane = t & 63;
  const int wave = t >> 6;
  const int wm = (wave >> 1) * 64;
  const int wn = (wave & 1) * 64;
  const int quad = lane >> 4;
  const int ln = lane & 15;

  f32x4 acc[4][4] = {};

  // staging: unit u -> row u>>2, chunk (u&3); fetch global chunk (u&3)^((row>>1)&3)
  const int u0 = t, u1 = t + 256;
  const int r0s = u0 >> 2, c0s = (u0 & 3) ^ ((r0s >> 1) & 3);
  const int r1s = u1 >> 2, c1s = (u1 & 3) ^ ((r1s >> 1) & 3);
  const unsigned short* gA0 = Ab + (size_t)(m0 + r0s)*1024 + c0s*8;
  const unsigned short* gA1 = Ab + (size_t)(m0 + r1s)*1024 + c1s*8;
  const unsigned short* gB0 = Wb + (size_t)(n0 + r0s)*1024 + c0s*8;
  const unsigned short* gB1 = Wb + (size_t)(n0 + r1s)*1024 + c1s*8;
  las_t lA0 = (las_t)(As + u0*8), lA1 = (las_t)(As + u1*8);
  las_t lB0 = (las_t)(Bs + u0*8), lB1 = (las_t)(Bs + u1*8);

  // reader: row = w?+i*16+ln, chunk quad -> slot quad^((ln>>1)&3)  (wm/wn/i*16 vanish mod 4)
  const int swz = (quad ^ ((ln >> 1) & 3)) * 8;
  const unsigned short* fa[4];
  const unsigned short* fb[4];
  #pragma unroll
  for (int i = 0; i < 4; ++i){
    fa[i] = As + (wm + i*16 + ln)*32 + swz;
    fb[i] = Bs + (wn + i*16 + ln)*32 + swz;
  }

  for (int k0 = 0; k0 < 1024; k0 += 32){
    __syncthreads();
    __builtin_amdgcn_global_load_lds((gas_t)(gA0 + k0), lA0, 16, 0, 0);
    __builtin_amdgcn_global_load_lds((gas_t)(gA1 + k0), lA1, 16, 0, 0);
    __builtin_amdgcn_global_load_lds((gas_t)(gB0 + k0), lB0, 16, 0, 0);
    __builtin_amdgcn_global_load_lds((gas_t)(gB1 + k0), lB1, 16, 0, 0);
    __syncthreads();
    bf16x8 av[4], bv[4];
    #pragma unroll
    for (int i = 0; i < 4; ++i){
      av[i] = *(const bf16x8*)fa[i];
      bv[i] = *(const bf16x8*)fb[i];
    }
    #pragma unroll
    for (int i = 0; i < 4; ++i)
      #pragma unroll
      for (int j = 0; j < 4; ++j)
        acc[i][j] = __builtin_amdgcn_mfma_f32_16x16x32_bf16(av[i], bv[j], acc[i][j], 0, 0, 0);
  }

  if (MODE == 0){
    const size_t PSZ = (size_t)32*16*512*64;
    if (p < 2){
      #pragma unroll
      for (int j = 0; j < 4; ++j){
        const int e  = n0 + wn + j*16 + ln;
        const int h  = e >> 6;
        const int eh = e & 63;
        const float invf = exp2f(-0.41524101f * (float)(eh >> 1)); // 10000^(-2i/64)
        unsigned short* outp = qkvout + ((((size_t)p*32 + b)*16 + h)*512)*64 + eh;
        #pragma unroll
        for (int i = 0; i < 4; ++i){
          #pragma unroll
          for (int r = 0; r < 4; ++r){
            const int l = m0 + wm + i*16 + quad*4 + r;
            const float own = acc[i][j][r];
            const float par = __shfl_xor(own, 1, 64);
            float sn, cs;
            __sincosf((float)l * invf, &sn, &cs);
            const float v = (e & 1) ? fmaf(own, cs, par*sn) : fmaf(own, cs, -par*sn);
            outp[(size_t)l*64] = f2bf(v);
          }
        }
      }
    } else {
      // vT[b][h][d][l]: pack 4 consecutive l (r=0..3) into one 8B store
      #pragma unroll
      for (int j = 0; j < 4; ++j){
        const int e  = n0 + wn + j*16 + ln;
        const int h  = e >> 6;
        const int eh = e & 63;
        unsigned short* outp = qkvout + 2*PSZ + (((size_t)b*16 + h)*64 + eh)*512;
        #pragma unroll
        for (int i = 0; i < 4; ++i){
          const int l0 = m0 + wm + i*16 + quad*4;
          ushort4 pk;
          pk.x = f2bf(acc[i][j][0]); pk.y = f2bf(acc[i][j][1]);
          pk.z = f2bf(acc[i][j][2]); pk.w = f2bf(acc[i][j][3]);
          *(ushort4*)(outp + l0) = pk;
        }
      }
    }
  } else {
    #pragma unroll
    for (int j = 0; j < 4; ++j){
      const int e = n0 + wn + j*16 + ln;
      #pragma unroll
      for (int i = 0; i < 4; ++i){
        #pragma unroll
        for (int r = 0; r < 4; ++r){
          const int l = m0 + wm + i*16 + quad*4 + r;
          outf[((size_t)b*512 + l)*1024 + e] = acc[i][j][r];
        }
      }
    }
  }
}

// ---------------- bf16 MFMA flash attention, 128-row Q blocks ----------------
// Block=(qt128,h,b), 4 waves; wave owns rows {qt*128+rg*64+w*16 .. +15} for rg=0,1.
// Q in registers; K and vT double-buffered via global_load_lds (xor-swizzled, 8 chunks/row);
// one barrier per 64-key tile. P round-trip through wave-local LDS (stride 72, 2-way free).

#define PSTR 72

__global__ __launch_bounds__(256, 3) void attn_kernel(
    const unsigned short* __restrict__ qkv,
    unsigned short* __restrict__ ctx)
{
  __shared__ __align__(16) unsigned short Ks[2][64*64];
  __shared__ __align__(16) unsigned short Vts[2][64*64];
  __shared__ __align__(16) unsigned short Ps[4][32*PSTR];

  const int qt = blockIdx.x, h = blockIdx.y, b = blockIdx.z;
  const size_t HO  = (((size_t)b)*16 + h)*512*64;
  const size_t PSZ = (size_t)32*16*512*64;
  const unsigned short* Qg  = qkv + HO;
  const unsigned short* Kg  = qkv + PSZ + HO;
  const unsigned short* Vtg = qkv + 2*PSZ + HO;   // [d][l], row stride 512

  const int t    = threadIdx.x;
  const int lane = t & 63;
  const int wave = t >> 6;
  const int quad = lane >> 4;
  const int ln   = lane & 15;

  // staging: unit u -> row u>>3, chunk u&7; fetch global chunk (u&7)^(row&7)
  const int u0 = t, u1 = t + 256;
  const int kr0 = u0 >> 3, kc0 = (u0 & 7) ^ (kr0 & 7);
  const int kr1 = u1 >> 3, kc1 = (u1 & 7) ^ (kr1 & 7);

  // Q fragments (A-layout) straight from global
  bf16x8 aq[2][2];
  #pragma unroll
  for (int rg = 0; rg < 2; ++rg){
    const int row = qt*128 + rg*64 + wave*16 + ln;
    #pragma unroll
    for (int ks = 0; ks < 2; ++ks)
      aq[rg][ks] = *(const bf16x8*)(Qg + (size_t)row*64 + ks*32 + quad*8);
  }

  const int ktEnd = 2*qt + 1;

  // prefetch kt=0
  __builtin_amdgcn_global_load_lds((gas_t)(Kg  + kr0*64  + kc0*8), (las_t)(Ks[0]  + u0*8), 16,0,0);
  __builtin_amdgcn_global_load_lds((gas_t)(Kg  + kr1*64  + kc1*8), (las_t)(Ks[0]  + u1*8), 16,0,0);
  __builtin_amdgcn_global_load_lds((gas_t)(Vtg + kr0*512 + kc0*8), (las_t)(Vts[0] + u0*8), 16,0,0);
  __builtin_amdgcn_global_load_lds((gas_t)(Vtg + kr1*512 + kc1*8), (las_t)(Vts[0] + u1*8), 16,0,0);

  float m_r[2][4], l_r[2][4];
  #pragma unroll
  for (int rg = 0; rg < 2; ++rg)
    #pragma unroll
    for (int r = 0; r < 4; ++r){ m_r[rg][r] = -3e38f; l_r[rg][r] = 0.f; }
  f32x4 o[2][4] = {};

  const int swzl = ln & 7;            // reader xor (row&7 == ln&7 for rows kn*16+ln / dn*16+ln)
  unsigned short* Pw = Ps[wave];
  const int rowoff = wave*16 + quad*4;

  for (int kt = 0; kt <= ktEnd; ++kt){
    __syncthreads();                  // drains kt's loads; protects other buffer's readers
    if (kt < ktEnd){
      const unsigned short* Kn  = Kg + (kt+1)*4096;
      const int col = (kt+1)*64;
      unsigned short* kb = Ks[(kt+1)&1];
      unsigned short* vb = Vts[(kt+1)&1];
      __builtin_amdgcn_global_load_lds((gas_t)(Kn  + kr0*64 + kc0*8),        (las_t)(kb + u0*8), 16,0,0);
      __builtin_amdgcn_global_load_lds((gas_t)(Kn  + kr1*64 + kc1*8),        (las_t)(kb + u1*8), 16,0,0);
      __builtin_amdgcn_global_load_lds((gas_t)(Vtg + kr0*512 + col + kc0*8), (las_t)(vb + u0*8), 16,0,0);
      __builtin_amdgcn_global_load_lds((gas_t)(Vtg + kr1*512 + col + kc1*8), (las_t)(vb + u1*8), 16,0,0);
    }
    const unsigned short* ks_ = Ks[kt&1];
    const unsigned short* vt_ = Vts[kt&1];

    #pragma unroll
    for (int rg = 0; rg < 2; ++rg){
      if (rg == 0 && kt > 2*qt) continue;       // rg0 fully masked only at kt==ktEnd
      const bool diag = (kt == 2*qt + rg);

      f32x4 s[4] = {};
      #pragma unroll
      for (int ks2 = 0; ks2 < 2; ++ks2){
        #pragma unroll
        for (int kn = 0; kn < 4; ++kn){
          const bf16x8 bk = *(const bf16x8*)(ks_ + (kn*16+ln)*64 + (((quad + ks2*4) ^ swzl))*8);
          s[kn] = __builtin_amdgcn_mfma_f32_16x16x32_bf16(aq[rg][ks2], bk, s[kn], 0, 0, 0);
        }
      }

      float p[4][4], lm[4] = {-3e38f,-3e38f,-3e38f,-3e38f};
      #pragma unroll
      for (int kn = 0; kn < 4; ++kn){
        const int col = kn*16 + ln;
        #pragma unroll
        for (int r = 0; r < 4; ++r){
          float v = s[kn][r] * 0.125f;
          if (diag && col > rowoff + r) v = -1e9f;
          p[kn][r] = v;
          lm[r] = fmaxf(lm[r], v);
        }
      }
      #pragma unroll
      for (int off = 1; off < 16; off <<= 1)
        #pragma unroll
        for (int r = 0; r < 4; ++r)
          lm[r] = fmaxf(lm[r], __shfl_xor(lm[r], off, 64));
      float alpha[4], rsum[4];
      #pragma unroll
      for (int r = 0; r < 4; ++r){
        const float mn = fmaxf(m_r[rg][r], lm[r]);
        alpha[r] = __expf(m_r[rg][r] - mn);
        m_r[rg][r] = mn;
      }
      #pragma unroll
      for (int kn = 0; kn < 4; ++kn)
        #pragma unroll
        for (int r = 0; r < 4; ++r)
          p[kn][r] = __expf(p[kn][r] - m_r[rg][r]);
      #pragma unroll
      for (int r = 0; r < 4; ++r)
        rsum[r] = (p[0][r] + p[1][r]) + (p[2][r] + p[3][r]);
      #pragma unroll
      for (int off = 1; off < 16; off <<= 1)
        #pragma unroll
        for (int r = 0; r < 4; ++r)
          rsum[r] += __shfl_xor(rsum[r], off, 64);
      #pragma unroll
      for (int r = 0; r < 4; ++r) l_r[rg][r] = l_r[rg][r]*alpha[r] + rsum[r];
      #pragma unroll
      for (int dn = 0; dn < 4; ++dn)
        #pragma unroll
        for (int r = 0; r < 4; ++r)
          o[rg][dn][r] *= alpha[r];

      // P: C-layout -> wave-local LDS [row-in-rg 0..31][key], A-layout source
      #pragma unroll
      for (int kn = 0; kn < 4; ++kn)
        #pragma unroll
        for (int r = 0; r < 4; ++r)
          Pw[(rg*16 + quad*4 + r)*PSTR + kn*16 + ln] = f2bf(p[kn][r]);

      #pragma unroll
      for (int ks2 = 0; ks2 < 2; ++ks2){
        const bf16x8 ap = *(const bf16x8*)(Pw + (rg*16 + ln)*PSTR + quad*8 + ks2*32);
        #pragma unroll
        for (int dn = 0; dn < 4; ++dn){
          const bf16x8 bv = *(const bf16x8*)(vt_ + (dn*16+ln)*64 + (((quad + ks2*4) ^ swzl))*8);
          o[rg][dn] = __builtin_amdgcn_mfma_f32_16x16x32_bf16(ap, bv, o[rg][dn], 0, 0, 0);
        }
      }
    }
  }

  #pragma unroll
  for (int rg = 0; rg < 2; ++rg){
    #pragma unroll
    for (int r = 0; r < 4; ++r){
      const float inv = 1.0f / l_r[rg][r];
      const int row = qt*128 + rg*64 + wave*16 + quad*4 + r;
      unsigned short* op = ctx + ((size_t)b*512 + row)*1024 + h*64 + ln;
      #pragma unroll
      for (int dn = 0; dn < 4; ++dn)
        op[dn*16] = f2bf(o[rg][dn][r] * inv);
    }
  }
}

// ---------------- launch ----------------

extern "C" void kernel_launch(void* const* d_in, const int* in_sizes, int n_in,
                              void* d_out, int out_size, void* d_ws, size_t ws_size,
                              hipStream_t stream) {
  const float* x     = (const float*)d_in[0];
  const float* qw    = (const float*)d_in[1];
  const float* kw    = (const float*)d_in[2];
  const float* vw    = (const float*)d_in[3];
  const float* ow    = (const float*)d_in[4];
  const float* rw    = (const float*)d_in[5];
  const float* rbias = (const float*)d_in[6];
  float* out = (float*)d_out;
  char* ws = (char*)d_ws;

  float* part            = (float*)(ws + OFF_PART);
  int* routes            = (int*)(ws + OFF_ROUTES);
  unsigned short* xb     = (unsigned short*)(ws + OFF_XB);
  unsigned short* wt     = (unsigned short*)(ws + OFF_WT);
  unsigned short* qkvbuf = (unsigned short*)(ws + OFF_QKV);
  unsigned short* ctx    = xb;
  float* probs = out + (size_t)32*512*1024;

  meanpool_kernel<<<dim3(32, 16), 256, 0, stream>>>(x, part, xb);
  router_kernel<<<32, 256, 0, stream>>>(part, rw, rbias, probs, routes);
  wcast_kernel<<<dim3(32, 32, 8), 256, 0, stream>>>(qw, wt);
  wcast_kernel<<<dim3(32, 32, 8), 256, 0, stream>>>(kw, wt + (size_t)8*1024*1024);
  wcast_kernel<<<dim3(32, 32, 8), 256, 0, stream>>>(vw, wt + (size_t)16*1024*1024);
  wcast_kernel<<<dim3(32, 32, 8), 256, 0, stream>>>(ow, wt + (size_t)24*1024*1024);
  gemm_kernel<0><<<dim3(8, 4, 96), 256, 0, stream>>>(xb, wt, routes, qkvbuf, nullptr);
  attn_kernel<<<dim3(4, 16, 32), 256, 0, stream>>>(qkvbuf, ctx);
  gemm_kernel<1><<<dim3(8, 4, 32), 256, 0, stream>>>(ctx, wt + (size_t)24*1024*1024, routes,
                                                     nullptr, out);
}